// Round 13
// baseline (207.042 us; speedup 1.0000x reference)
//
#include <hip/hip_runtime.h>

typedef __bf16 bf16;
typedef __bf16 bf16x8 __attribute__((ext_vector_type(8)));
typedef float f32x4 __attribute__((ext_vector_type(4)));
typedef unsigned u32x4 __attribute__((ext_vector_type(4)));

#define MFMA16(a, b, c) __builtin_amdgcn_mfma_f32_16x16x32_bf16((a), (b), (c), 0, 0, 0)

static __device__ __forceinline__ bf16x8 ldg8(const bf16* p) {
  return *(const bf16x8*)p;
}
static __device__ __forceinline__ unsigned cvt_pk_bf16(float lo, float hi) {
  unsigned d;
  asm("v_cvt_pk_bf16_f32 %0, %1, %2" : "=v"(d) : "v"(lo), "v"(hi));
  return d;
}
static __device__ __forceinline__ void pl32_swap(unsigned& a, unsigned& b) {
  asm("v_permlane32_swap_b32 %0, %1" : "+v"(a), "+v"(b));
}
static __device__ __forceinline__ void pl16_swap(unsigned& a, unsigned& b) {
  asm("v_permlane16_swap_b32 %0, %1" : "+v"(a), "+v"(b));
}

// ===========================================================================
// Ladder: 803 -> ... -> 190.5 (r12 best: B-prefetch +2us; flash 79.6).
// Floor audit r12: flash LDS-port ~50us (10 b128/wave-tile, 10.2MB/CU),
// VALU ~41us, MFMA ~23us -> LDS port binds, measured 79.6 at ~65% port
// util. r13: HALVE LDS bytes/work -- 64 q rows/wave (K/V frag reads are
// q-invariant; all 4 m-tiles share one k0/k1/bv read). Block covers 256 q;
// grid 1024 (16 strip x 16 bh x 4 qtr, bijective XCD swizzle). aq[4][2],
// o[4][4], s[4][2]: VGPR ~150-170 -> NO min-waves clause (r10 lesson);
// 3 waves/SIMD natural, flash proven occupancy-invariant 2.8-8 (r9/r11).
// New floors: VALU 41 > LDS 25 -> predict flash 62-72us. Opart blocks now
// 256 rows; out_gemm combine indexing updated (m = 64*mt algebra checked).
// qkv/out GEMM cores + prep = r12-proven, untouched.
// ===========================================================================

// ---- prep: bx<16 -> pack W (fp32 [K][N]) into P32T tiles (nt<12 Wqkv,
// else Wout); bx>=16 -> cvt x (fp32 [8192][512]) into P32 tiles Xp. ----
__global__ __launch_bounds__(256) void prep(const float* __restrict__ Wqkv,
                                            const float* __restrict__ Wout,
                                            const float* __restrict__ x,
                                            bf16* __restrict__ Wp1,
                                            bf16* __restrict__ Wp2,
                                            bf16* __restrict__ Xp) {
  __shared__ float tile[32 * 129];
  if (blockIdx.x < 16) {
    int kc = blockIdx.x, nt = blockIdx.y;
    const float* W;
    bf16* dst;
    int N, ntl;
    if (nt < 12) {
      W = Wqkv; N = 1536; ntl = nt;
      dst = Wp1 + ((size_t)ntl * 16 + kc) * 4096;
    } else {
      W = Wout; N = 512; ntl = nt - 12;
      dst = Wp2 + ((size_t)ntl * 16 + kc) * 4096;
    }
    int row = threadIdx.x >> 3;
    int c0 = (threadIdx.x & 7) * 16;
    const float* src = W + (size_t)(kc * 32 + row) * N + ntl * 128 + c0;
#pragma unroll
    for (int i = 0; i < 4; i++) {
      float4 v = *(const float4*)(src + i * 4);
      tile[row * 129 + c0 + i * 4 + 0] = v.x;
      tile[row * 129 + c0 + i * 4 + 1] = v.y;
      tile[row * 129 + c0 + i * 4 + 2] = v.z;
      tile[row * 129 + c0 + i * 4 + 3] = v.w;
    }
    __syncthreads();
#pragma unroll
    for (int half = 0; half < 2; half++) {
      int U = threadIdx.x + half * 256;
      int kchunk = U >> 7, n = U & 127;
      bf16x8 o;
#pragma unroll
      for (int j = 0; j < 8; j++) o[j] = (bf16)tile[(kchunk * 8 + j) * 129 + n];
      *(bf16x8*)&dst[U * 8] = o;
    }
  } else {
    // cvt_pack_x: tile(mt,kc)=128x32, addr = kchunk*1024 + r*8 + kk
    int mt = blockIdx.x - 16, kc = blockIdx.y;
    int r = threadIdx.x >> 1;
    int khalf = threadIdx.x & 1;
    const float* src = x + (size_t)(mt * 128 + r) * 512 + kc * 32 + khalf * 16;
    float4 v0 = *(const float4*)(src + 0);
    float4 v1 = *(const float4*)(src + 4);
    float4 v2 = *(const float4*)(src + 8);
    float4 v3 = *(const float4*)(src + 12);
    bf16* dt = Xp + ((size_t)mt * 16 + kc) * 4096;
    bf16x8 a, b;
    a[0] = (bf16)v0.x; a[1] = (bf16)v0.y; a[2] = (bf16)v0.z; a[3] = (bf16)v0.w;
    a[4] = (bf16)v1.x; a[5] = (bf16)v1.y; a[6] = (bf16)v1.z; a[7] = (bf16)v1.w;
    b[0] = (bf16)v2.x; b[1] = (bf16)v2.y; b[2] = (bf16)v2.z; b[3] = (bf16)v2.w;
    b[4] = (bf16)v3.x; b[5] = (bf16)v3.y; b[6] = (bf16)v3.z; b[7] = (bf16)v3.w;
    int kc0 = khalf * 2;
    *(bf16x8*)&dt[(kc0 + 0) * 1024 + r * 8] = a;
    *(bf16x8*)&dt[(kc0 + 1) * 1024 + r * 8] = b;
  }
}

// ---------------------------------------------------------------------------
// QKV projection (r12-proven, unchanged), 128x128 tiles. Grid (64,12).
// A staged from packed Xp (one-barrier dbuf); B-frags register-prefetched
// one k-step ahead. Epilogue: LDS round-trip, coalesced 16B stores.
// Q pre-scaled by 0.125*log2e.
// ---------------------------------------------------------------------------
__global__ __launch_bounds__(256, 3) void qkv_gemm(const bf16* __restrict__ Xp,
                                                   const bf16* __restrict__ Wp1,
                                                   const float* __restrict__ bqkv,
                                                   bf16* __restrict__ Q,
                                                   bf16* __restrict__ Kh,
                                                   bf16* __restrict__ Vt) {
  int mt = blockIdx.x, nt = blockIdx.y;
  int tid = threadIdx.x;
  int wave = tid >> 6, lane = tid & 63;
  int l16 = lane & 15, quad = lane >> 4;
  int wr = wave >> 1, wc = wave & 1;

  __shared__ __align__(16) bf16 SM[9216];  // A dbuf 2x4096; epilogue T 128x72

  const bf16* At = Xp + (size_t)mt * 16 * 4096;
  const bf16* Bt = Wp1 + (size_t)nt * 16 * 4096;

  bf16x8 pa0 = ldg8(At + tid * 8);
  bf16x8 pa1 = ldg8(At + 2048 + tid * 8);
  int boff[4];
#pragma unroll
  for (int fj = 0; fj < 4; fj++)
    boff[fj] = (quad * 128 + wc * 64 + fj * 16 + l16) * 8;
  bf16x8 pb[4];
#pragma unroll
  for (int fj = 0; fj < 4; fj++) pb[fj] = ldg8(Bt + boff[fj]);

  f32x4 acc[4][4] = {};
#pragma unroll 2
  for (int kc = 0; kc < 16; kc++) {
    bf16* A = SM + (kc & 1) * 4096;
    *(bf16x8*)&A[tid * 8] = pa0;
    *(bf16x8*)&A[2048 + tid * 8] = pa1;
    __syncthreads();
    if (kc < 15) {
      const bf16* an = At + (kc + 1) * 4096;
      pa0 = ldg8(an + tid * 8);
      pa1 = ldg8(an + 2048 + tid * 8);
    }
    bf16x8 af[4];
#pragma unroll
    for (int fi = 0; fi < 4; fi++)
      af[fi] = *(const bf16x8*)&A[(quad * 128 + wr * 64 + fi * 16 + l16) * 8];
    __builtin_amdgcn_s_setprio(1);
#pragma unroll
    for (int fi = 0; fi < 4; fi++)
#pragma unroll
      for (int fj = 0; fj < 4; fj++)
        acc[fi][fj] = MFMA16(af[fi], pb[fj], acc[fi][fj]);
    __builtin_amdgcn_s_setprio(0);
    if (kc < 15) {  // prefetch B(kc+1) AFTER last use of pb
      const bf16* bn = Bt + (kc + 1) * 4096;
#pragma unroll
      for (int fj = 0; fj < 4; fj++) pb[fj] = ldg8(bn + boff[fj]);
    }
  }

  // ---- epilogue: LDS round-trip, coalesced 16B stores ----
  __syncthreads();
  const int TS = 72;
  int b = mt >> 5;

  if (nt < 8) {
    bool isQ = nt < 4;
    bf16* dstb = isQ ? Q : Kh;
    int hb = isQ ? nt * 2 : (nt - 4) * 2;
#pragma unroll
    for (int ph = 0; ph < 2; ph++) {
      if (wc == ph) {
#pragma unroll
        for (int fj = 0; fj < 4; fj++) {
          float bias = bqkv[nt * 128 + wc * 64 + fj * 16 + l16];
#pragma unroll
          for (int fi = 0; fi < 4; fi++)
#pragma unroll
            for (int rr = 0; rr < 4; rr++) {
              float v = acc[fi][fj][rr] + bias;
              if (isQ) v *= 0.18033688f;  // 0.125*log2e
              SM[(wr * 64 + fi * 16 + quad * 4 + rr) * TS + fj * 16 + l16] =
                  (bf16)v;
            }
        }
      }
      __syncthreads();
      int bh = b * 8 + hb + ph;
      bf16* dh = dstb + (size_t)bh * 4096 * 64 + (size_t)((mt & 31) * 128) * 64;
#pragma unroll
      for (int i = 0; i < 4; i++) {
        int U = tid + i * 256;
        int mr = U >> 3, oct = U & 7;
        bf16x8 v = ldg8(&SM[mr * TS + oct * 8]);
        *(bf16x8*)&dh[(size_t)mr * 64 + oct * 8] = v;
      }
      __syncthreads();
    }
  } else {
    int h0 = (nt - 8) * 2;
#pragma unroll
    for (int ph = 0; ph < 2; ph++) {
      if (wr == ph) {
#pragma unroll
        for (int fj = 0; fj < 4; fj++) {
          float bias = bqkv[nt * 128 + wc * 64 + fj * 16 + l16];
          int cp = wc * 64 + fj * 16 + l16;
#pragma unroll
          for (int fi = 0; fi < 4; fi++)
#pragma unroll
            for (int rr = 0; rr < 4; rr++)
              SM[cp * TS + fi * 16 + quad * 4 + rr] =
                  (bf16)(acc[fi][fj][rr] + bias);
        }
      }
      __syncthreads();
      int nb = (mt & 31) * 2 + ph;
#pragma unroll
      for (int i = 0; i < 4; i++) {
        int U = tid + i * 256;
        int cp = U >> 3, oct = U & 7;
        int h = h0 + (cp >> 6), d = cp & 63;
        int bh = b * 8 + h;
        bf16x8 v = ldg8(&SM[cp * TS + oct * 8]);
        *(bf16x8*)&Vt[(((size_t)bh * 64 + nb) * 64 + d) * 64 + oct * 8] = v;
      }
      __syncthreads();
    }
  }
}

// ---------------------------------------------------------------------------
// flash_partial v22: 64 q rows/wave (halves LDS bytes/work -- K/V frag
// reads are q-invariant, shared across all 4 m-tiles). Grid 1024 (16 strip
// x 16 bh x 4 qtr; bijective XCD chunked swizzle). 32 KV-tiles of 32.
// QK(16 MFMA, k0/k1 read once per c2) -> SM(4 mt) -> PV+l(20 MFMA, bv read
// once per ct). K/V dbuf 16KB, one barrier/tile, reg-prefetch after it.
// NO min-waves clause: VGPR ~150-170 natural (r10 lesson), 3 waves/SIMD.
// Opart blocks 256 rows x 64 (ub*16384); Lpart ub*256.
// ---------------------------------------------------------------------------
__global__ __launch_bounds__(256) void flash_partial(const bf16* __restrict__ Q,
                                                     const bf16* __restrict__ K,
                                                     const bf16* __restrict__ Vt,
                                                     bf16* __restrict__ Opart,
                                                     float* __restrict__ Lpart) {
  int i = blockIdx.x;
  int swz = (i & 7) * 128 + (i >> 3);  // bijective: 1024 % 8 == 0
  int qtr = swz & 3;
  int strip = (swz >> 2) & 15;
  int bh = swz >> 6;
  int tid = threadIdx.x;
  int wave = tid >> 6, lane = tid & 63;
  int l16 = lane & 15, quad = lane >> 4;

  const bf16* Qh = Q + (size_t)bh * 4096 * 64;
  const bf16* Kg = K + ((size_t)bh * 4096 + qtr * 1024) * 64;
  const bf16* Vg = Vt + (size_t)bh * 64 * 4096 + (size_t)qtr * 1024 * 64;

  __shared__ __align__(16) bf16 Klds[2][2048];
  __shared__ __align__(16) bf16 Vlds[2][2048];

  int qbase = strip * 256 + wave * 64;
  bf16x8 aq[4][2];
#pragma unroll
  for (int mt = 0; mt < 4; mt++) {
    const bf16* qr = Qh + (size_t)(qbase + mt * 16 + l16) * 64;
    aq[mt][0] = ldg8(qr + quad * 8);
    aq[mt][1] = ldg8(qr + 32 + quad * 8);
  }

  bf16x8 ones;
#pragma unroll
  for (int j = 0; j < 8; j++) ones[j] = (bf16)1.0f;

  f32x4 o[4][4] = {};
  f32x4 acc_l[4] = {};

  // staging units (swizzled, conflict-free writes)
  int ku = (tid >> 3) * 8 + ((tid & 7) ^ ((tid >> 3) & 7));
  int vd = tid >> 2, vc8 = (tid & 3) * 8;
  int vu = vd * 4 + ((tid & 3) ^ ((vd >> 1) & 3));

  bf16x8 kp = ldg8(Kg + tid * 8);
  bf16x8 vp = ldg8(Vg + (size_t)vd * 64 + vc8);

  for (int t = 0; t < 32; t++) {
    bf16* kl = Klds[t & 1];
    bf16* vl = Vlds[t & 1];
    *(bf16x8*)&kl[ku * 8] = kp;
    *(bf16x8*)&vl[vu * 8] = vp;
    __syncthreads();

    if (t < 31) {
      kp = ldg8(Kg + (size_t)(t + 1) * 2048 + tid * 8);
      vp = ldg8(Vg + (size_t)((t + 1) >> 1) * 4096 + ((t + 1) & 1) * 32 +
                (size_t)vd * 64 + vc8);
    }

    // ---- S^T = K Q^T (swapped operands), 32 kv x 64 q ----
    f32x4 s[4][2] = {};
    __builtin_amdgcn_s_setprio(1);
#pragma unroll
    for (int c2 = 0; c2 < 2; c2++) {
      int n = c2 * 16 + l16;  // kv row in tile
      bf16x8 k0 = *(const bf16x8*)&kl[(n * 8 + (quad ^ (n & 7))) * 8];
      bf16x8 k1 = *(const bf16x8*)&kl[(n * 8 + ((4 + quad) ^ (n & 7))) * 8];
#pragma unroll
      for (int mt = 0; mt < 4; mt++) {
        s[mt][c2] = MFMA16(k0, aq[mt][0], s[mt][c2]);
        s[mt][c2] = MFMA16(k1, aq[mt][1], s[mt][c2]);
      }
    }
    __builtin_amdgcn_s_setprio(0);

    // ---- p = exp2(s); pack+redistribute to PV A-frags ----
    bf16x8 pa[4];
#pragma unroll
    for (int mt = 0; mt < 4; mt++) {
      unsigned ue[2], wo[2];
#pragma unroll
      for (int c2 = 0; c2 < 2; c2++) {
        float p0 = __builtin_amdgcn_exp2f(s[mt][c2][0]);
        float p1 = __builtin_amdgcn_exp2f(s[mt][c2][1]);
        float p2 = __builtin_amdgcn_exp2f(s[mt][c2][2]);
        float p3 = __builtin_amdgcn_exp2f(s[mt][c2][3]);
        ue[c2] = cvt_pk_bf16(p0, p1);
        wo[c2] = cvt_pk_bf16(p2, p3);
      }
      pl32_swap(ue[0], ue[1]);
      pl16_swap(ue[0], ue[1]);
      pl32_swap(wo[0], wo[1]);
      pl16_swap(wo[0], wo[1]);
      u32x4 pk = {ue[0], wo[0], ue[1], wo[1]};
      pa[mt] = __builtin_bit_cast(bf16x8, pk);
    }

    // ---- O += P V; l += P ones (bv read once per ct, shared by 4 mt) ----
    __builtin_amdgcn_s_setprio(1);
#pragma unroll
    for (int mt = 0; mt < 4; mt++)
      acc_l[mt] = MFMA16(pa[mt], ones, acc_l[mt]);
#pragma unroll
    for (int ct = 0; ct < 4; ct++) {
      int d = ct * 16 + l16;
      bf16x8 bv = *(const bf16x8*)&vl[(d * 4 + (quad ^ ((d >> 1) & 3))) * 8];
#pragma unroll
      for (int mt = 0; mt < 4; mt++)
        o[mt][ct] = MFMA16(pa[mt], bv, o[mt][ct]);
    }
    __builtin_amdgcn_s_setprio(0);
  }

  // ---- epilogue: partial o (bf16) + l (fp32, shuffle-free) ----
  size_t ub = ((size_t)qtr * 16 + bh) * 16 + strip;
  bf16* op = Opart + ub * 16384;
#pragma unroll
  for (int mt = 0; mt < 4; mt++) {
#pragma unroll
    for (int ct = 0; ct < 4; ct++)
#pragma unroll
      for (int r = 0; r < 4; r++)
        op[(wave * 64 + mt * 16 + quad * 4 + r) * 64 + ct * 16 + l16] =
            (bf16)o[mt][ct][r];
    if (l16 == 0) {
#pragma unroll
      for (int r = 0; r < 4; r++)
        Lpart[ub * 256 + wave * 64 + mt * 16 + quad * 4 + r] = acc_l[mt][r];
    }
  }
}

// ---------------------------------------------------------------------------
// Output projection + FUSED 4-way combine: 64x128 tiles, grid (128, 4) =
// 512 blocks = 2/CU. A-staging computes sum_q(o_q)/sum_q(l_q) from Opart/
// Lpart (256-row blocks: strip=(mt&63)>>2, r=(mt&3)*64+lane; m=64*mt).
// B-frags register-prefetched one k-step ahead.
// ---------------------------------------------------------------------------
__global__ __launch_bounds__(256, 4) void out_gemm(const bf16* __restrict__ Opart,
                                                   const float* __restrict__ Lpart,
                                                   const bf16* __restrict__ Wp2,
                                                   const float* __restrict__ bout,
                                                   float* __restrict__ Out) {
  int mt = blockIdx.x, nt = blockIdx.y;
  int tid = threadIdx.x;
  int wave = tid >> 6, lane = tid & 63;
  int l16 = lane & 15, quad = lane >> 4;
  int b = mt >> 6;
  int strip = (mt & 63) >> 2;
  int r = (mt & 3) * 64 + lane;  // row within 256-row Opart block

  __shared__ __align__(16) bf16 SM[2][2048];

  const bf16* Bt = Wp2 + (size_t)nt * 16 * 4096;

  int boff[2];
#pragma unroll
  for (int fj = 0; fj < 2; fj++)
    boff[fj] = (quad * 128 + wave * 32 + fj * 16 + l16) * 8;
  bf16x8 pbo[2];
#pragma unroll
  for (int fj = 0; fj < 2; fj++) pbo[fj] = ldg8(Bt + boff[fj]);

  bf16x8 po[4];
  float pls;
  {
    int bh = b * 8;  // kc = 0: h = 0, d0 = 0
    pls = 0.f;
#pragma unroll
    for (int q = 0; q < 4; q++) {
      size_t u = ((size_t)q * 16 + bh) * 16 + strip;
      po[q] = ldg8(&Opart[u * 16384 + r * 64 + wave * 8]);
      pls += Lpart[u * 256 + r];
    }
  }

  f32x4 acc[4][2] = {};
#pragma unroll 2
  for (int kc = 0; kc < 16; kc++) {
    bf16* A = SM[kc & 1];
    float rl = 1.0f / pls;
    float sj[8];
#pragma unroll
    for (int j = 0; j < 8; j++)
      sj[j] = (((float)po[0][j] + (float)po[1][j]) +
               ((float)po[2][j] + (float)po[3][j])) * rl;
    u32x4 pk = {cvt_pk_bf16(sj[0], sj[1]), cvt_pk_bf16(sj[2], sj[3]),
                cvt_pk_bf16(sj[4], sj[5]), cvt_pk_bf16(sj[6], sj[7])};
    *(bf16x8*)&A[tid * 8] = __builtin_bit_cast(bf16x8, pk);
    __syncthreads();
    if (kc < 15) {
      int kn = kc + 1;
      int h = kn >> 1, d0 = (kn & 1) * 32;
      int bh = b * 8 + h;
      pls = 0.f;
#pragma unroll
      for (int q = 0; q < 4; q++) {
        size_t u = ((size_t)q * 16 + bh) * 16 + strip;
        po[q] = ldg8(&Opart[u * 16384 + r * 64 + d0 + wave * 8]);
        pls += Lpart[u * 256 + r];
      }
    }
    bf16x8 af[4];
#pragma unroll
    for (int fi = 0; fi < 4; fi++)
      af[fi] = *(const bf16x8*)&A[(quad * 64 + fi * 16 + l16) * 8];
    __builtin_amdgcn_s_setprio(1);
#pragma unroll
    for (int fi = 0; fi < 4; fi++)
#pragma unroll
      for (int fj = 0; fj < 2; fj++)
        acc[fi][fj] = MFMA16(af[fi], pbo[fj], acc[fi][fj]);
    __builtin_amdgcn_s_setprio(0);
    if (kc < 15) {  // prefetch B(kc+1) AFTER last use of pbo
      const bf16* bn = Bt + (kc + 1) * 4096;
#pragma unroll
      for (int fj = 0; fj < 2; fj++) pbo[fj] = ldg8(bn + boff[fj]);
    }
  }

#pragma unroll
  for (int fj = 0; fj < 2; fj++) {
    int c = nt * 128 + wave * 32 + fj * 16 + l16;
    float bias = bout[c];
#pragma unroll
    for (int fi = 0; fi < 4; fi++) {
#pragma unroll
      for (int rr = 0; rr < 4; rr++) {
        int m = mt * 64 + fi * 16 + quad * 4 + rr;
        Out[(size_t)m * 512 + c] = acc[fi][fj][rr] + bias;
      }
    }
  }
}

// ---------------------------------------------------------------------------
// ws layout (lifetime-overlapped, r5-proven; end 60,293,120 < 61.4MB):
//   Q 0 (8.39M) | K 8388608 | Vt 16777216 | Wp2 25165824 (0.52M) |
//   Opart 25690112 (33.55M) | Lpart 59244544 (1.05M)
//   Xp 25690112 (8.39M, dead after qkv) | Wp1 34078720 (1.57M, dead after
//   qkv) -- both inside Opart region, clobbered only when flash writes it.
// ---------------------------------------------------------------------------
extern "C" void kernel_launch(void* const* d_in, const int* in_sizes, int n_in,
                              void* d_out, int out_size, void* d_ws,
                              size_t ws_size, hipStream_t stream) {
  const float* x = (const float*)d_in[0];
  const float* w_qkv = (const float*)d_in[1];
  const float* b_qkv = (const float*)d_in[2];
  const float* w_out = (const float*)d_in[3];
  const float* b_out = (const float*)d_in[4];
  float* out = (float*)d_out;

  char* ws = (char*)d_ws;
  bf16* Q = (bf16*)(ws + 0);
  bf16* K = (bf16*)(ws + 8388608);
  bf16* Vt = (bf16*)(ws + 16777216);
  bf16* Wp2 = (bf16*)(ws + 25165824);
  bf16* Opart = (bf16*)(ws + 25690112);
  float* Lpart = (float*)(ws + 59244544);
  bf16* Xp = (bf16*)(ws + 25690112);   // overlays Opart region, dead pre-flash
  bf16* Wp1 = (bf16*)(ws + 34078720);  // overlays Opart region, dead pre-flash

  prep<<<dim3(80, 16), 256, 0, stream>>>(w_qkv, w_out, x, Wp1, Wp2, Xp);
  qkv_gemm<<<dim3(64, 12), 256, 0, stream>>>(Xp, Wp1, b_qkv, Q, K, Vt);
  flash_partial<<<dim3(1024), 256, 0, stream>>>(Q, K, Vt, Opart, Lpart);
  out_gemm<<<dim3(128, 4), 256, 0, stream>>>(Opart, Lpart, Wp2, b_out, out);
}

// Round 14
// 193.246 us; speedup vs baseline: 1.0714x; 1.0714x over previous
//
#include <hip/hip_runtime.h>

typedef __bf16 bf16;
typedef __bf16 bf16x8 __attribute__((ext_vector_type(8)));
typedef float f32x4 __attribute__((ext_vector_type(4)));
typedef unsigned u32x4 __attribute__((ext_vector_type(4)));

#define MFMA16(a, b, c) __builtin_amdgcn_mfma_f32_16x16x32_bf16((a), (b), (c), 0, 0, 0)

static __device__ __forceinline__ bf16x8 ldg8(const bf16* p) {
  return *(const bf16x8*)p;
}
static __device__ __forceinline__ unsigned cvt_pk_bf16(float lo, float hi) {
  unsigned d;
  asm("v_cvt_pk_bf16_f32 %0, %1, %2" : "=v"(d) : "v"(lo), "v"(hi));
  return d;
}
static __device__ __forceinline__ void pl32_swap(unsigned& a, unsigned& b) {
  asm("v_permlane32_swap_b32 %0, %1" : "+v"(a), "+v"(b));
}
static __device__ __forceinline__ void pl16_swap(unsigned& a, unsigned& b) {
  asm("v_permlane16_swap_b32 %0, %1" : "+v"(a), "+v"(b));
}

// ===========================================================================
// Ladder: 803 -> ... -> 190.5 (r12 BEST) -> r13 207 FAILED (64 q rows/wave:
// VGPR 56->120, occupancy 34->19%, serial softmax chain x4 per wave-tile;
// MfmaUtil 41->30 -- LDS-byte savings < dependency-chain/occupancy loss).
// r14 = EXACT REVERT to r12. Flash saddle point confirmed from three
// directions: r9 (FETCH 73->16MB, dur flat -> not memory-bound), r11
// (occupancy 2.8->8 blocks/CU capable, dur flat -> not TLP-bound), r13
// (wider waves, dur worse -> chain-bound at ~94% MFMA+VALU issue).
// Remaining: ~30-40us harness-fixed dispatch overhead + deep-pipeline
// rewrite as the only unexplored (high-risk) direction.
// ===========================================================================

// ---- prep: bx<16 -> pack W (fp32 [K][N]) into P32T tiles (nt<12 Wqkv,
// else Wout); bx>=16 -> cvt x (fp32 [8192][512]) into P32 tiles Xp. ----
__global__ __launch_bounds__(256) void prep(const float* __restrict__ Wqkv,
                                            const float* __restrict__ Wout,
                                            const float* __restrict__ x,
                                            bf16* __restrict__ Wp1,
                                            bf16* __restrict__ Wp2,
                                            bf16* __restrict__ Xp) {
  __shared__ float tile[32 * 129];
  if (blockIdx.x < 16) {
    int kc = blockIdx.x, nt = blockIdx.y;
    const float* W;
    bf16* dst;
    int N, ntl;
    if (nt < 12) {
      W = Wqkv; N = 1536; ntl = nt;
      dst = Wp1 + ((size_t)ntl * 16 + kc) * 4096;
    } else {
      W = Wout; N = 512; ntl = nt - 12;
      dst = Wp2 + ((size_t)ntl * 16 + kc) * 4096;
    }
    int row = threadIdx.x >> 3;
    int c0 = (threadIdx.x & 7) * 16;
    const float* src = W + (size_t)(kc * 32 + row) * N + ntl * 128 + c0;
#pragma unroll
    for (int i = 0; i < 4; i++) {
      float4 v = *(const float4*)(src + i * 4);
      tile[row * 129 + c0 + i * 4 + 0] = v.x;
      tile[row * 129 + c0 + i * 4 + 1] = v.y;
      tile[row * 129 + c0 + i * 4 + 2] = v.z;
      tile[row * 129 + c0 + i * 4 + 3] = v.w;
    }
    __syncthreads();
#pragma unroll
    for (int half = 0; half < 2; half++) {
      int U = threadIdx.x + half * 256;
      int kchunk = U >> 7, n = U & 127;
      bf16x8 o;
#pragma unroll
      for (int j = 0; j < 8; j++) o[j] = (bf16)tile[(kchunk * 8 + j) * 129 + n];
      *(bf16x8*)&dst[U * 8] = o;
    }
  } else {
    // cvt_pack_x: tile(mt,kc)=128x32, addr = kchunk*1024 + r*8 + kk
    int mt = blockIdx.x - 16, kc = blockIdx.y;
    int r = threadIdx.x >> 1;
    int khalf = threadIdx.x & 1;
    const float* src = x + (size_t)(mt * 128 + r) * 512 + kc * 32 + khalf * 16;
    float4 v0 = *(const float4*)(src + 0);
    float4 v1 = *(const float4*)(src + 4);
    float4 v2 = *(const float4*)(src + 8);
    float4 v3 = *(const float4*)(src + 12);
    bf16* dt = Xp + ((size_t)mt * 16 + kc) * 4096;
    bf16x8 a, b;
    a[0] = (bf16)v0.x; a[1] = (bf16)v0.y; a[2] = (bf16)v0.z; a[3] = (bf16)v0.w;
    a[4] = (bf16)v1.x; a[5] = (bf16)v1.y; a[6] = (bf16)v1.z; a[7] = (bf16)v1.w;
    b[0] = (bf16)v2.x; b[1] = (bf16)v2.y; b[2] = (bf16)v2.z; b[3] = (bf16)v2.w;
    b[4] = (bf16)v3.x; b[5] = (bf16)v3.y; b[6] = (bf16)v3.z; b[7] = (bf16)v3.w;
    int kc0 = khalf * 2;
    *(bf16x8*)&dt[(kc0 + 0) * 1024 + r * 8] = a;
    *(bf16x8*)&dt[(kc0 + 1) * 1024 + r * 8] = b;
  }
}

// ---------------------------------------------------------------------------
// QKV projection, 128x128 tiles. Grid (64,12). A staged from packed Xp
// (one-barrier dbuf); B-frags register-prefetched one k-step ahead
// (primed pre-loop, reloaded right AFTER the MFMA cluster). Epilogue:
// LDS round-trip, coalesced 16B stores. Q pre-scaled 0.125*log2e.
// ---------------------------------------------------------------------------
__global__ __launch_bounds__(256, 3) void qkv_gemm(const bf16* __restrict__ Xp,
                                                   const bf16* __restrict__ Wp1,
                                                   const float* __restrict__ bqkv,
                                                   bf16* __restrict__ Q,
                                                   bf16* __restrict__ Kh,
                                                   bf16* __restrict__ Vt) {
  int mt = blockIdx.x, nt = blockIdx.y;
  int tid = threadIdx.x;
  int wave = tid >> 6, lane = tid & 63;
  int l16 = lane & 15, quad = lane >> 4;
  int wr = wave >> 1, wc = wave & 1;

  __shared__ __align__(16) bf16 SM[9216];  // A dbuf 2x4096; epilogue T 128x72

  const bf16* At = Xp + (size_t)mt * 16 * 4096;
  const bf16* Bt = Wp1 + (size_t)nt * 16 * 4096;

  bf16x8 pa0 = ldg8(At + tid * 8);
  bf16x8 pa1 = ldg8(At + 2048 + tid * 8);
  int boff[4];
#pragma unroll
  for (int fj = 0; fj < 4; fj++)
    boff[fj] = (quad * 128 + wc * 64 + fj * 16 + l16) * 8;
  bf16x8 pb[4];
#pragma unroll
  for (int fj = 0; fj < 4; fj++) pb[fj] = ldg8(Bt + boff[fj]);

  f32x4 acc[4][4] = {};
#pragma unroll 2
  for (int kc = 0; kc < 16; kc++) {
    bf16* A = SM + (kc & 1) * 4096;
    *(bf16x8*)&A[tid * 8] = pa0;
    *(bf16x8*)&A[2048 + tid * 8] = pa1;
    __syncthreads();
    if (kc < 15) {
      const bf16* an = At + (kc + 1) * 4096;
      pa0 = ldg8(an + tid * 8);
      pa1 = ldg8(an + 2048 + tid * 8);
    }
    bf16x8 af[4];
#pragma unroll
    for (int fi = 0; fi < 4; fi++)
      af[fi] = *(const bf16x8*)&A[(quad * 128 + wr * 64 + fi * 16 + l16) * 8];
    __builtin_amdgcn_s_setprio(1);
#pragma unroll
    for (int fi = 0; fi < 4; fi++)
#pragma unroll
      for (int fj = 0; fj < 4; fj++)
        acc[fi][fj] = MFMA16(af[fi], pb[fj], acc[fi][fj]);
    __builtin_amdgcn_s_setprio(0);
    if (kc < 15) {  // prefetch B(kc+1) AFTER last use of pb
      const bf16* bn = Bt + (kc + 1) * 4096;
#pragma unroll
      for (int fj = 0; fj < 4; fj++) pb[fj] = ldg8(bn + boff[fj]);
    }
  }

  // ---- epilogue: LDS round-trip, coalesced 16B stores ----
  __syncthreads();
  const int TS = 72;
  int b = mt >> 5;

  if (nt < 8) {
    bool isQ = nt < 4;
    bf16* dstb = isQ ? Q : Kh;
    int hb = isQ ? nt * 2 : (nt - 4) * 2;
#pragma unroll
    for (int ph = 0; ph < 2; ph++) {
      if (wc == ph) {
#pragma unroll
        for (int fj = 0; fj < 4; fj++) {
          float bias = bqkv[nt * 128 + wc * 64 + fj * 16 + l16];
#pragma unroll
          for (int fi = 0; fi < 4; fi++)
#pragma unroll
            for (int rr = 0; rr < 4; rr++) {
              float v = acc[fi][fj][rr] + bias;
              if (isQ) v *= 0.18033688f;  // 0.125*log2e
              SM[(wr * 64 + fi * 16 + quad * 4 + rr) * TS + fj * 16 + l16] =
                  (bf16)v;
            }
        }
      }
      __syncthreads();
      int bh = b * 8 + hb + ph;
      bf16* dh = dstb + (size_t)bh * 4096 * 64 + (size_t)((mt & 31) * 128) * 64;
#pragma unroll
      for (int i = 0; i < 4; i++) {
        int U = tid + i * 256;
        int mr = U >> 3, oct = U & 7;
        bf16x8 v = ldg8(&SM[mr * TS + oct * 8]);
        *(bf16x8*)&dh[(size_t)mr * 64 + oct * 8] = v;
      }
      __syncthreads();
    }
  } else {
    int h0 = (nt - 8) * 2;
#pragma unroll
    for (int ph = 0; ph < 2; ph++) {
      if (wr == ph) {
#pragma unroll
        for (int fj = 0; fj < 4; fj++) {
          float bias = bqkv[nt * 128 + wc * 64 + fj * 16 + l16];
          int cp = wc * 64 + fj * 16 + l16;
#pragma unroll
          for (int fi = 0; fi < 4; fi++)
#pragma unroll
            for (int rr = 0; rr < 4; rr++)
              SM[cp * TS + fi * 16 + quad * 4 + rr] =
                  (bf16)(acc[fi][fj][rr] + bias);
        }
      }
      __syncthreads();
      int nb = (mt & 31) * 2 + ph;
#pragma unroll
      for (int i = 0; i < 4; i++) {
        int U = tid + i * 256;
        int cp = U >> 3, oct = U & 7;
        int h = h0 + (cp >> 6), d = cp & 63;
        int bh = b * 8 + h;
        bf16x8 v = ldg8(&SM[cp * TS + oct * 8]);
        *(bf16x8*)&Vt[(((size_t)bh * 64 + nb) * 64 + d) * 64 + oct * 8] = v;
      }
      __syncthreads();
    }
  }
}

// ---------------------------------------------------------------------------
// flash_partial (r11/r12-proven, FROZEN): Grid 2048, XCD chunked swizzle.
// Per block: (bh, strip 128 q, qtr 1024 kv), 32 KV-tiles of 32. QK(8 MFMA)
// -> SM -> PV+l(10). In-reg P, exp2, ones-MFMA rowsum. K/V dbuf, one
// barrier/tile. launch_bounds(256,4): VGPR natural ~56 (G1).
// ---------------------------------------------------------------------------
__global__ __launch_bounds__(256, 4) void flash_partial(const bf16* __restrict__ Q,
                                                        const bf16* __restrict__ K,
                                                        const bf16* __restrict__ Vt,
                                                        bf16* __restrict__ Opart,
                                                        float* __restrict__ Lpart) {
  int i = blockIdx.x;
  int swz = (i & 7) * 256 + (i >> 3);  // bijective: 2048 % 8 == 0
  int qtr = swz & 3;
  int strip = (swz >> 2) & 31;
  int bh = swz >> 7;
  int tid = threadIdx.x;
  int wave = tid >> 6, lane = tid & 63;
  int l16 = lane & 15, quad = lane >> 4;

  const bf16* Qh = Q + (size_t)bh * 4096 * 64;
  const bf16* Kg = K + ((size_t)bh * 4096 + qtr * 1024) * 64;
  const bf16* Vg = Vt + (size_t)bh * 64 * 4096 + (size_t)qtr * 1024 * 64;

  __shared__ __align__(16) bf16 Klds[2][2048];
  __shared__ __align__(16) bf16 Vlds[2][2048];

  int qbase = strip * 128 + wave * 32;
  bf16x8 aq[2][2];
#pragma unroll
  for (int mt = 0; mt < 2; mt++) {
    const bf16* qr = Qh + (size_t)(qbase + mt * 16 + l16) * 64;
    aq[mt][0] = ldg8(qr + quad * 8);
    aq[mt][1] = ldg8(qr + 32 + quad * 8);
  }

  bf16x8 ones;
#pragma unroll
  for (int j = 0; j < 8; j++) ones[j] = (bf16)1.0f;

  f32x4 o[2][4] = {};
  f32x4 acc_l[2] = {};

  // staging units (swizzled, conflict-free writes)
  int ku = (tid >> 3) * 8 + ((tid & 7) ^ ((tid >> 3) & 7));
  int vd = tid >> 2, vc8 = (tid & 3) * 8;
  int vu = vd * 4 + ((tid & 3) ^ ((vd >> 1) & 3));

  bf16x8 kp = ldg8(Kg + tid * 8);
  bf16x8 vp = ldg8(Vg + (size_t)vd * 64 + vc8);

#pragma unroll 2
  for (int t = 0; t < 32; t++) {
    bf16* kl = Klds[t & 1];
    bf16* vl = Vlds[t & 1];
    *(bf16x8*)&kl[ku * 8] = kp;
    *(bf16x8*)&vl[vu * 8] = vp;
    __syncthreads();

    if (t < 31) {
      kp = ldg8(Kg + (size_t)(t + 1) * 2048 + tid * 8);
      vp = ldg8(Vg + (size_t)((t + 1) >> 1) * 4096 + ((t + 1) & 1) * 32 +
                (size_t)vd * 64 + vc8);
    }

    // ---- S^T = K Q^T (swapped operands), 32 kv ----
    f32x4 s[2][2] = {};
    __builtin_amdgcn_s_setprio(1);
#pragma unroll
    for (int c2 = 0; c2 < 2; c2++) {
      int n = c2 * 16 + l16;  // kv row in tile
      bf16x8 k0 = *(const bf16x8*)&kl[(n * 8 + (quad ^ (n & 7))) * 8];
      bf16x8 k1 = *(const bf16x8*)&kl[(n * 8 + ((4 + quad) ^ (n & 7))) * 8];
#pragma unroll
      for (int mt = 0; mt < 2; mt++) {
        s[mt][c2] = MFMA16(k0, aq[mt][0], s[mt][c2]);
        s[mt][c2] = MFMA16(k1, aq[mt][1], s[mt][c2]);
      }
    }
    __builtin_amdgcn_s_setprio(0);

    // ---- p = exp2(s); pack+redistribute to PV A-frags ----
    bf16x8 pa[2];
#pragma unroll
    for (int mt = 0; mt < 2; mt++) {
      unsigned ue[2], wo[2];
#pragma unroll
      for (int c2 = 0; c2 < 2; c2++) {
        float p0 = __builtin_amdgcn_exp2f(s[mt][c2][0]);
        float p1 = __builtin_amdgcn_exp2f(s[mt][c2][1]);
        float p2 = __builtin_amdgcn_exp2f(s[mt][c2][2]);
        float p3 = __builtin_amdgcn_exp2f(s[mt][c2][3]);
        ue[c2] = cvt_pk_bf16(p0, p1);
        wo[c2] = cvt_pk_bf16(p2, p3);
      }
      pl32_swap(ue[0], ue[1]);
      pl16_swap(ue[0], ue[1]);
      pl32_swap(wo[0], wo[1]);
      pl16_swap(wo[0], wo[1]);
      u32x4 pk = {ue[0], wo[0], ue[1], wo[1]};
      pa[mt] = __builtin_bit_cast(bf16x8, pk);
    }

    // ---- O += P V; l += P ones ----
    __builtin_amdgcn_s_setprio(1);
    acc_l[0] = MFMA16(pa[0], ones, acc_l[0]);
    acc_l[1] = MFMA16(pa[1], ones, acc_l[1]);
#pragma unroll
    for (int ct = 0; ct < 4; ct++) {
      int d = ct * 16 + l16;
      bf16x8 bv = *(const bf16x8*)&vl[(d * 4 + (quad ^ ((d >> 1) & 3))) * 8];
      o[0][ct] = MFMA16(pa[0], bv, o[0][ct]);
      o[1][ct] = MFMA16(pa[1], bv, o[1][ct]);
    }
    __builtin_amdgcn_s_setprio(0);
  }

  // ---- epilogue: partial o (bf16) + l (fp32, shuffle-free) ----
  size_t ub = ((size_t)qtr * 16 + bh) * 32 + strip;
  bf16* op = Opart + ub * 8192;
#pragma unroll
  for (int mt = 0; mt < 2; mt++) {
#pragma unroll
    for (int ct = 0; ct < 4; ct++)
#pragma unroll
      for (int r = 0; r < 4; r++)
        op[(wave * 32 + mt * 16 + quad * 4 + r) * 64 + ct * 16 + l16] =
            (bf16)o[mt][ct][r];
    if (l16 == 0) {
#pragma unroll
      for (int r = 0; r < 4; r++)
        Lpart[ub * 128 + wave * 32 + mt * 16 + quad * 4 + r] = acc_l[mt][r];
    }
  }
}

// ---------------------------------------------------------------------------
// Output projection + FUSED 4-way combine: 64x128 tiles, grid (128, 4) =
// 512 blocks = 2/CU. A-staging computes sum_q(o_q)/sum_q(l_q) from Opart/
// Lpart. B-frags register-prefetched one k-step ahead (same pattern as qkv).
// ---------------------------------------------------------------------------
__global__ __launch_bounds__(256, 4) void out_gemm(const bf16* __restrict__ Opart,
                                                   const float* __restrict__ Lpart,
                                                   const bf16* __restrict__ Wp2,
                                                   const float* __restrict__ bout,
                                                   float* __restrict__ Out) {
  int mt = blockIdx.x, nt = blockIdx.y;
  int tid = threadIdx.x;
  int wave = tid >> 6, lane = tid & 63;
  int l16 = lane & 15, quad = lane >> 4;
  int mt128 = mt >> 1, mhalf = mt & 1;
  int b = mt128 >> 5, strip = mt128 & 31;
  int r = mhalf * 64 + lane;

  __shared__ __align__(16) bf16 SM[2][2048];

  const bf16* Bt = Wp2 + (size_t)nt * 16 * 4096;

  int boff[2];
#pragma unroll
  for (int fj = 0; fj < 2; fj++)
    boff[fj] = (quad * 128 + wave * 32 + fj * 16 + l16) * 8;
  bf16x8 pbo[2];
#pragma unroll
  for (int fj = 0; fj < 2; fj++) pbo[fj] = ldg8(Bt + boff[fj]);

  bf16x8 po[4];
  float pls;
  {
    int bh = b * 8;  // kc = 0: h = 0, d0 = 0
    pls = 0.f;
#pragma unroll
    for (int q = 0; q < 4; q++) {
      size_t u = ((size_t)q * 16 + bh) * 32 + strip;
      po[q] = ldg8(&Opart[u * 8192 + r * 64 + wave * 8]);
      pls += Lpart[u * 128 + r];
    }
  }

  f32x4 acc[4][2] = {};
#pragma unroll 2
  for (int kc = 0; kc < 16; kc++) {
    bf16* A = SM[kc & 1];
    float rl = 1.0f / pls;
    float sj[8];
#pragma unroll
    for (int j = 0; j < 8; j++)
      sj[j] = (((float)po[0][j] + (float)po[1][j]) +
               ((float)po[2][j] + (float)po[3][j])) * rl;
    u32x4 pk = {cvt_pk_bf16(sj[0], sj[1]), cvt_pk_bf16(sj[2], sj[3]),
                cvt_pk_bf16(sj[4], sj[5]), cvt_pk_bf16(sj[6], sj[7])};
    *(bf16x8*)&A[tid * 8] = __builtin_bit_cast(bf16x8, pk);
    __syncthreads();
    if (kc < 15) {
      int kn = kc + 1;
      int h = kn >> 1, d0 = (kn & 1) * 32;
      int bh = b * 8 + h;
      pls = 0.f;
#pragma unroll
      for (int q = 0; q < 4; q++) {
        size_t u = ((size_t)q * 16 + bh) * 32 + strip;
        po[q] = ldg8(&Opart[u * 8192 + r * 64 + d0 + wave * 8]);
        pls += Lpart[u * 128 + r];
      }
    }
    bf16x8 af[4];
#pragma unroll
    for (int fi = 0; fi < 4; fi++)
      af[fi] = *(const bf16x8*)&A[(quad * 64 + fi * 16 + l16) * 8];
    __builtin_amdgcn_s_setprio(1);
#pragma unroll
    for (int fi = 0; fi < 4; fi++)
#pragma unroll
      for (int fj = 0; fj < 2; fj++)
        acc[fi][fj] = MFMA16(af[fi], pbo[fj], acc[fi][fj]);
    __builtin_amdgcn_s_setprio(0);
    if (kc < 15) {  // prefetch B(kc+1) AFTER last use of pbo
      const bf16* bn = Bt + (kc + 1) * 4096;
#pragma unroll
      for (int fj = 0; fj < 2; fj++) pbo[fj] = ldg8(bn + boff[fj]);
    }
  }

#pragma unroll
  for (int fj = 0; fj < 2; fj++) {
    int c = nt * 128 + wave * 32 + fj * 16 + l16;
    float bias = bout[c];
#pragma unroll
    for (int fi = 0; fi < 4; fi++) {
#pragma unroll
      for (int rr = 0; rr < 4; rr++) {
        int m = mt * 64 + fi * 16 + quad * 4 + rr;
        Out[(size_t)m * 512 + c] = acc[fi][fj][rr] + bias;
      }
    }
  }
}

// ---------------------------------------------------------------------------
// ws layout (lifetime-overlapped, r5-proven; end 60,293,120 < 61.4MB):
//   Q 0 (8.39M) | K 8388608 | Vt 16777216 | Wp2 25165824 (0.52M) |
//   Opart 25690112 (33.55M) | Lpart 59244544 (1.05M)
//   Xp 25690112 (8.39M, dead after qkv) | Wp1 34078720 (1.57M, dead after
//   qkv) -- both inside Opart region, clobbered only when flash writes it.
// ---------------------------------------------------------------------------
extern "C" void kernel_launch(void* const* d_in, const int* in_sizes, int n_in,
                              void* d_out, int out_size, void* d_ws,
                              size_t ws_size, hipStream_t stream) {
  const float* x = (const float*)d_in[0];
  const float* w_qkv = (const float*)d_in[1];
  const float* b_qkv = (const float*)d_in[2];
  const float* w_out = (const float*)d_in[3];
  const float* b_out = (const float*)d_in[4];
  float* out = (float*)d_out;

  char* ws = (char*)d_ws;
  bf16* Q = (bf16*)(ws + 0);
  bf16* K = (bf16*)(ws + 8388608);
  bf16* Vt = (bf16*)(ws + 16777216);
  bf16* Wp2 = (bf16*)(ws + 25165824);
  bf16* Opart = (bf16*)(ws + 25690112);
  float* Lpart = (float*)(ws + 59244544);
  bf16* Xp = (bf16*)(ws + 25690112);   // overlays Opart region, dead pre-flash
  bf16* Wp1 = (bf16*)(ws + 34078720);  // overlays Opart region, dead pre-flash

  prep<<<dim3(80, 16), 256, 0, stream>>>(w_qkv, w_out, x, Wp1, Wp2, Xp);
  qkv_gemm<<<dim3(64, 12), 256, 0, stream>>>(Xp, Wp1, b_qkv, Q, K, Vt);
  flash_partial<<<dim3(2048), 256, 0, stream>>>(Q, K, Vt, Opart, Lpart);
  out_gemm<<<dim3(128, 4), 256, 0, stream>>>(Opart, Lpart, Wp2, b_out, out);
}